// Round 5
// baseline (511.949 us; speedup 1.0000x reference)
//
#include <hip/hip_runtime.h>

typedef __bf16 bf16;
typedef __bf16 bf16x8 __attribute__((ext_vector_type(8)));
typedef __bf16 bf16x4 __attribute__((ext_vector_type(4)));
typedef float  f32x4  __attribute__((ext_vector_type(4)));

#define EPSBN 1e-5f

// ---------------- async global->LDS (16B per lane) ----------------
__device__ __forceinline__ void gload16(const void* gp, void* lp) {
  __builtin_amdgcn_global_load_lds(
      (__attribute__((address_space(1))) void*)(unsigned long long)gp,
      (__attribute__((address_space(3))) void*)(unsigned)(unsigned long long)lp,
      16, 0, 0);
}

// ---------------- k_init: merged prep (wa/wc cast + BN fold + zero) | prepw | ring ----------------
__global__ __launch_bounds__(256) void k_init(
    const float* __restrict__ wa, const float* __restrict__ wc, const float* __restrict__ wb,
    const float* __restrict__ ga, const float* __restrict__ ba, const float* __restrict__ ma, const float* __restrict__ va,
    const float* __restrict__ gb, const float* __restrict__ bb, const float* __restrict__ mb, const float* __restrict__ vb,
    const float* __restrict__ gc, const float* __restrict__ bc, const float* __restrict__ mc, const float* __restrict__ vc,
    bf16* __restrict__ wa_bf, bf16* __restrict__ wc_bf, bf16* __restrict__ wb_bf,
    float* __restrict__ bn6, float* __restrict__ sums, unsigned* __restrict__ cnts,
    bf16* __restrict__ h1p)
{
  const int bid = blockIdx.x, tid = threadIdx.x;
  if (bid < 1024) {
    unsigned i = bid * 256 + tid;
    unsigned e = i * 4;
    float4 a = *(const float4*)(wa + e);
    bf16x4 av; av[0]=(bf16)a.x; av[1]=(bf16)a.y; av[2]=(bf16)a.z; av[3]=(bf16)a.w;
    *(bf16x4*)(wa_bf + e) = av;
    float4 c = *(const float4*)(wc + e);
    bf16x4 cv; cv[0]=(bf16)c.x; cv[1]=(bf16)c.y; cv[2]=(bf16)c.z; cv[3]=(bf16)c.w;
    *(bf16x4*)(wc_bf + e) = cv;
    if (i < 1024) {
      float s;
      s = ga[i] / sqrtf(va[i] + EPSBN); bn6[i]        = s; bn6[1024 + i] = ba[i] - ma[i] * s;
      s = gb[i] / sqrtf(vb[i] + EPSBN); bn6[2048 + i] = s; bn6[3072 + i] = bb[i] - mb[i] * s;
      s = gc[i] / sqrtf(vc[i] + EPSBN); bn6[4096 + i] = s; bn6[5120 + i] = bc[i] - mc[i] * s;
    }
    if (i < 32768) sums[i] = 0.f;
    if (i == 0) { cnts[0] = 0u; cnts[1] = 0u; }
  } else if (bid < 3328) {
    // prepw: wb fp32 [co][ci][3][3] -> bf16 frag layout [g*9+kk][co%64][ci]
    int t = (bid - 1024) * 256 + tid;          // 589824
    int ci = t & 63;
    int u  = t >> 6;
    int cl = u & 63;
    int gk = u >> 6;
    int g  = gk / 9, kk = gk - g * 9;
    wb_bf[t] = (bf16)wb[(((size_t)(g * 64 + cl) * 64) + ci) * 9 + kk];
  } else {
    // ring: zero the 1-pixel pad ring of h1p [32][30][30][1024]
    int t = (bid - 3328) * 256 + tid;          // 475136 = 32*116*128
    int c8 = t & 127;
    int r  = (t >> 7) % 116;
    int b  = t / (116 * 128);
    int y, x;
    if (r < 30)      { y = 0;      x = r; }
    else if (r < 60) { y = 29;     x = r - 30; }
    else if (r < 88) { y = r - 59; x = 0; }
    else             { y = r - 87; x = 29; }
    size_t off = (((size_t)b * 30 + y) * 30 + x) * 1024 + (size_t)c8 * 8;
    *(uint4*)(h1p + off) = uint4{0, 0, 0, 0};
  }
}

// ---------------- k_cast_pool: x NCHW fp32 -> xT [P][1024] bf16, + 4x4 avgpool -> pooledb bf16 ----------------
__global__ __launch_bounds__(256) void k_cast_pool(
    const float* __restrict__ x, bf16* __restrict__ xT, bf16* __restrict__ pooledb)
{
  const int pt = blockIdx.x, ct = blockIdx.y, b = blockIdx.z;   // 7,16,32
  __shared__ float tile[64 * 116];
  const int tid = threadIdx.x;
  const float* src = x + ((size_t)(b * 1024 + ct * 64)) * 784 + pt * 112;
  #pragma unroll
  for (int it = 0; it < 7; it++) {
    unsigned f = tid + it * 256;
    unsigned ci = f / 28, j = f % 28;
    float4 v = *(const float4*)(src + (size_t)ci * 784 + j * 4);
    *(float4*)(tile + ci * 116 + j * 4) = v;
  }
  __syncthreads();
  bf16* dst = xT + ((size_t)(b * 784 + pt * 112)) * 1024 + ct * 64;
  for (int s = tid; s < 896; s += 256) {
    int j = s >> 3, c8 = s & 7;
    bf16x8 tmp;
    #pragma unroll
    for (int e = 0; e < 8; e++) tmp[e] = (bf16)tile[(c8 * 8 + e) * 116 + j];
    *(bf16x8*)(dst + (size_t)j * 1024 + c8 * 8) = tmp;
  }
  for (int s = tid; s < 448; s += 256) {
    int c = s / 7, ox = s % 7;
    float acc = 0.f;
    #pragma unroll
    for (int yy = 0; yy < 4; yy++)
      #pragma unroll
      for (int xx = 0; xx < 4; xx++)
        acc += tile[c * 116 + yy * 28 + ox * 4 + xx];
    pooledb[((size_t)b * 49 + pt * 7 + ox) * 1024 + ct * 64 + c] = (bf16)(acc * (1.0f / 16.0f));
  }
}

// ---------------- k_mask: logits (coalesced bf16 dots), mask7, dilation, counts ----------------
__global__ __launch_bounds__(256) void k_mask(
    const bf16* __restrict__ pooledb, const float* __restrict__ mkw, const float* __restrict__ mkb,
    float* __restrict__ mask7, unsigned* __restrict__ cnts)
{
  const int b = blockIdx.x, tid = threadIdx.x;
  const int lane = tid & 63, w = tid >> 6;
  __shared__ float l0s[49], l1s[49];
  __shared__ unsigned char m7[56];
  float w0r[16], w1r[16];
  #pragma unroll
  for (int i = 0; i < 4; i++) {
    *(f32x4*)(w0r + i * 4) = *(const f32x4*)(mkw + lane * 16 + i * 4);
    *(f32x4*)(w1r + i * 4) = *(const f32x4*)(mkw + 1024 + lane * 16 + i * 4);
  }
  const float mkb0 = mkb[0], mkb1 = mkb[1];
  for (int p = w; p < 49; p += 4) {
    const bf16* pp = pooledb + ((size_t)b * 49 + p) * 1024 + lane * 16;
    bf16x8 h0 = *(const bf16x8*)pp;
    bf16x8 h1 = *(const bf16x8*)(pp + 8);
    float a0 = 0.f, a1 = 0.f;
    #pragma unroll
    for (int e = 0; e < 8; e++) {
      float v0 = (float)h0[e], v1 = (float)h1[e];
      a0 += v0 * w0r[e] + v1 * w0r[8 + e];
      a1 += v0 * w1r[e] + v1 * w1r[8 + e];
    }
    #pragma unroll
    for (int d = 1; d < 64; d <<= 1) { a0 += __shfl_xor(a0, d); a1 += __shfl_xor(a1, d); }
    if (lane == 0) { l0s[p] = a0 + mkb0; l1s[p] = a1 + mkb1; }
  }
  __syncthreads();
  if (tid < 49) {
    unsigned char m = (l0s[tid] >= l1s[tid]) ? 1 : 0;
    m7[tid] = m;
    mask7[b * 49 + tid] = (float)m;
  }
  __syncthreads();
  if (tid < 64) {
    unsigned long long bal = __ballot((tid < 49) && m7[tid]);
    if (tid == 0) atomicAdd(&cnts[0], (unsigned)__popcll(bal));
  }
  int cnt = 0;
  for (int p2 = tid; p2 < 784; p2 += 256) {
    int y = p2 / 28, x = p2 % 28;
    int cy0 = (y == 0) ? 0 : (y - 1) >> 2, cy1 = (y == 27) ? 6 : (y + 1) >> 2;
    int cx0 = (x == 0) ? 0 : (x - 1) >> 2, cx1 = (x == 27) ? 6 : (x + 1) >> 2;
    int d = 0;
    for (int cy = cy0; cy <= cy1; cy++)
      for (int cx = cx0; cx <= cx1; cx++) d |= m7[cy * 7 + cx];
    cnt += d;
  }
  #pragma unroll
  for (int d = 1; d < 64; d <<= 1) cnt += __shfl_xor(cnt, d);
  __shared__ int wsum[4];
  if (lane == 0) wsum[w] = cnt;
  __syncthreads();
  if (tid == 0) atomicAdd(&cnts[1], (unsigned)(wsum[0] + wsum[1] + wsum[2] + wsum[3]));
}

// ---------------- gemm body: D[m][n] = sum_k A[m][k]*B[n][k], 128x128 tile, BK=64 ----------------
// 1D grid 1568, 64-block supertiles. Rows (q*4+r) run along the contiguous output dim.
template<int MODE>
__device__ __forceinline__ void gemm_body(
    const bf16* __restrict__ Aop, const bf16* __restrict__ Bop, void* __restrict__ outp,
    const float* __restrict__ bn6, const float* __restrict__ xres,
    const float* __restrict__ mask7)
{
  int id = blockIdx.x, pixt, cot;
  if (id < 1536) { pixt = (id >> 6) * 8 + (id & 7); cot = (id >> 3) & 7; }
  else { int wi = id - 1536; pixt = 192 + (wi & 3); cot = wi >> 2; }
  const int mt = (MODE == 0) ? cot : pixt;
  const int nt = (MODE == 0) ? pixt : cot;

  __shared__ bf16 ldsA[8192];
  __shared__ bf16 ldsB[8192];
  const int tid = threadIdx.x, lane = tid & 63, w = tid >> 6;
  const int wm = w & 1, wn = w >> 1;
  const int li = lane & 15, q = lane >> 4;

  const bf16* Ab = Aop + (size_t)mt * 128 * 1024;
  const bf16* Bb = Bop + (size_t)nt * 128 * 1024;
  const bf16* ga[4]; const bf16* gb[4];
  #pragma unroll
  for (int j = 0; j < 4; j++) {
    int c = w * 256 + j * 64 + lane;
    int row = c >> 3, k8 = (c & 7) ^ (row & 7);
    ga[j] = Ab + (size_t)row * 1024 + k8 * 8;
    gb[j] = Bb + (size_t)row * 1024 + k8 * 8;
  }
  const int lb = li * 128 + ((q ^ (li & 7)) << 4);
  f32x4 acc[4][4] = {};

  for (int kt = 0; kt < 16; kt++) {
    #pragma unroll
    for (int j = 0; j < 4; j++) gload16(ga[j], (char*)ldsA + w * 4096 + j * 1024);
    #pragma unroll
    for (int j = 0; j < 4; j++) gload16(gb[j], (char*)ldsB + w * 4096 + j * 1024);
    #pragma unroll
    for (int j = 0; j < 4; j++) { ga[j] += 64; gb[j] += 64; }
    __syncthreads();
    #pragma unroll
    for (int ks = 0; ks < 2; ks++) {
      bf16x8 af[4], bfr[4];
      #pragma unroll
      for (int m = 0; m < 4; m++)
        af[m] = *(const bf16x8*)((const char*)ldsA + wm * 8192 + m * 2048 + (lb ^ (ks * 64)));
      #pragma unroll
      for (int n = 0; n < 4; n++)
        bfr[n] = *(const bf16x8*)((const char*)ldsB + wn * 8192 + n * 2048 + (lb ^ (ks * 64)));
      #pragma unroll
      for (int m = 0; m < 4; m++)
        #pragma unroll
        for (int n = 0; n < 4; n++)
          acc[m][n] = __builtin_amdgcn_mfma_f32_16x16x32_bf16(af[m], bfr[n], acc[m][n], 0, 0, 0);
    }
    __syncthreads();
  }

  if constexpr (MODE == 0) {
    bf16* h1p = (bf16*)outp;
    const int co0 = mt * 128 + wm * 64 + q * 4;
    f32x4 sv[4], ov[4];
    #pragma unroll
    for (int m = 0; m < 4; m++) {
      sv[m] = *(const f32x4*)(bn6 + co0 + m * 16);
      ov[m] = *(const f32x4*)(bn6 + 1024 + co0 + m * 16);
    }
    #pragma unroll
    for (int n = 0; n < 4; n++) {
      unsigned p = nt * 128 + wn * 64 + n * 16 + li;
      unsigned b = p / 784u, rem = p % 784u;
      unsigned y = rem / 28u, xx = rem % 28u;
      bf16* dst = h1p + (((size_t)b * 30 + y + 1) * 30 + xx + 1) * 1024 + co0;
      #pragma unroll
      for (int m = 0; m < 4; m++) {
        bf16x4 pk;
        #pragma unroll
        for (int r = 0; r < 4; r++)
          pk[r] = (bf16)fmaxf(acc[m][n][r] * sv[m][r] + ov[m][r], 0.f);
        *(bf16x4*)(dst + m * 16) = pk;
      }
    }
  } else {
    float* dst = (float*)outp;
    const int p0 = mt * 128 + wm * 64 + q * 4;
    int bM[4]; unsigned hwM[4]; float mvv[4];
    #pragma unroll
    for (int m = 0; m < 4; m++) {
      int pm = p0 + m * 16;
      int b = pm / 784; unsigned hw = pm - b * 784;
      bM[m] = b; hwM[m] = hw;
      unsigned y = hw / 28u, xx = hw % 28u;
      mvv[m] = mask7[b * 49 + (y >> 2) * 7 + (xx >> 2)];
    }
    #pragma unroll
    for (int n = 0; n < 4; n++) {
      int co = nt * 128 + wn * 64 + n * 16 + li;
      float s = bn6[4096 + co], o = bn6[5120 + co];
      #pragma unroll
      for (int m = 0; m < 4; m++) {
        size_t base = ((size_t)(bM[m] * 1024 + co)) * 784 + hwM[m];
        f32x4 xv = *(const f32x4*)(xres + base);
        f32x4 rv;
        #pragma unroll
        for (int r = 0; r < 4; r++) {
          float v = acc[m][n][r] * s + o;
          rv[r] = fmaxf(v * mvv[m] + xv[r], 0.f);
        }
        *(f32x4*)(dst + base) = rv;
      }
    }
  }
}

__global__ __launch_bounds__(256) void k_conv_a(
    const bf16* __restrict__ A, const bf16* __restrict__ B, void* __restrict__ o,
    const float* __restrict__ bn6)
{ gemm_body<0>(A, B, o, bn6, nullptr, nullptr); }

__global__ __launch_bounds__(256) void k_conv_c(
    const bf16* __restrict__ A, const bf16* __restrict__ B, void* __restrict__ o,
    const float* __restrict__ bn6, const float* __restrict__ xres, const float* __restrict__ mask7)
{ gemm_body<1>(A, B, o, bn6, xres, mask7); }

// ---------------- k_conv_b: grouped 3x3 + BN + ReLU + SE sums ----------------
// grid (32 b, 16 g, 4 yt): yt<3 -> 8 output rows (224 px), yt=3 -> 4 rows (112 px).
// Waves: h=w>>1 picks pixel-half, cg2=w&1 picks co-32-half. Each input frag read
// feeds 2 MFMAs (two co-16 groups, weights in regs loaded per-cs phase).
__global__ __launch_bounds__(256) void k_conv_b(
    const bf16* __restrict__ h1p, const bf16* __restrict__ wb_bf,
    bf16* __restrict__ h2T, float* __restrict__ sums, const float* __restrict__ bn6)
{
  const int b = blockIdx.x, g = blockIdx.y, yt = blockIdx.z;
  __shared__ bf16 ldsI[300 * 64];     // 38400 B, xor-swizzled [pos][ci]
  const int tid = threadIdx.x, lane = tid & 63, w = tid >> 6;
  const int li = lane & 15, q = lane >> 4;
  const int h = w >> 1, cg2 = w & 1;

  const bool full = (yt < 3);
  const int fullC  = full ? 37 : 22;            // full 1KB chunks; then one half chunk
  const int mcount = full ? 7 : (h ? 3 : 4);
  const int mbase  = full ? h * 7 : (h ? 4 : 0);

  // stage: padded rows 8yt .. 8yt+9 (yt<3) or 24..29 (yt=3)
  const bf16* iBase = h1p + (size_t)b * 921600 + (size_t)(8 * yt) * 30 * 1024 + g * 64;
  #pragma unroll
  for (int t = 0; t < 10; t++) {
    int j = w + t * 4;
    if (j < fullC || (j == fullC && lane < 32)) {
      int c = j * 64 + lane;
      int pos = c >> 3, ci8 = (c & 7) ^ (pos & 7);
      gload16(iBase + (size_t)pos * 1024 + ci8 * 8, (char*)ldsI + j * 1024);
    }
  }

  int pos0[7];
  #pragma unroll
  for (int i = 0; i < 7; i++) {
    int p = (mbase + i) * 16 + li;
    pos0[i] = (p / 28) * 30 + (p % 28);
  }
  __syncthreads();

  f32x4 acc[7][2] = {};
  const bf16* wbase = wb_bf + ((size_t)g * 9 * 64 + cg2 * 32 + li) * 64 + q * 8;
  #pragma unroll
  for (int cs = 0; cs < 2; cs++) {
    bf16x8 wcs[9][2];
    #pragma unroll
    for (int kk = 0; kk < 9; kk++)
      #pragma unroll
      for (int c2 = 0; c2 < 2; c2++)
        wcs[kk][c2] = *(const bf16x8*)(wbase + ((size_t)kk * 64 + c2 * 16) * 64 + cs * 32);
    #pragma unroll
    for (int kk = 0; kk < 9; kk++) {
      const int shift = (kk / 3) * 30 + (kk % 3);
      #pragma unroll
      for (int i = 0; i < 7; i++) {
        if (i < mcount) {
          int pos = pos0[i] + shift;
          int off = pos * 128 + ((((cs << 2) + q) ^ (pos & 7)) << 4);
          bf16x8 ifr = *(const bf16x8*)((const char*)ldsI + off);
          acc[i][0] = __builtin_amdgcn_mfma_f32_16x16x32_bf16(wcs[kk][0], ifr, acc[i][0], 0, 0, 0);
          acc[i][1] = __builtin_amdgcn_mfma_f32_16x16x32_bf16(wcs[kk][1], ifr, acc[i][1], 0, 0, 0);
        }
      }
    }
  }

  // epilogue: rows = co (q*4+r), cols = pixel (li)
  const int cobase = g * 64 + cg2 * 32;
  f32x4 sv[2], ov[2], csum[2];
  #pragma unroll
  for (int c2 = 0; c2 < 2; c2++) {
    sv[c2] = *(const f32x4*)(bn6 + 2048 + cobase + c2 * 16 + q * 4);
    ov[c2] = *(const f32x4*)(bn6 + 3072 + cobase + c2 * 16 + q * 4);
    csum[c2] = f32x4{0.f, 0.f, 0.f, 0.f};
  }
  #pragma unroll
  for (int i = 0; i < 7; i++) {
    if (i < mcount) {
      int pl = yt * 224 + (mbase + i) * 16 + li;
      bf16* dst = h2T + ((size_t)b * 784 + pl) * 1024 + cobase + q * 4;
      #pragma unroll
      for (int c2 = 0; c2 < 2; c2++) {
        bf16x4 pk;
        #pragma unroll
        for (int r = 0; r < 4; r++) {
          float v = fmaxf(acc[i][c2][r] * sv[c2][r] + ov[c2][r], 0.f);
          csum[c2][r] += v;
          pk[r] = (bf16)v;
        }
        *(bf16x4*)(dst + c2 * 16) = pk;
      }
    }
  }
  #pragma unroll
  for (int d = 1; d < 16; d <<= 1)
    #pragma unroll
    for (int c2 = 0; c2 < 2; c2++)
      #pragma unroll
      for (int r = 0; r < 4; r++) csum[c2][r] += __shfl_xor(csum[c2][r], d);
  if (li == 0) {
    #pragma unroll
    for (int c2 = 0; c2 < 2; c2++)
      #pragma unroll
      for (int r = 0; r < 4; r++)
        atomicAdd(&sums[b * 1024 + cobase + c2 * 16 + q * 4 + r], csum[c2][r]);
  }
}

// ---------------- k_se1: s1[b][256] = relu(sw1 . mean + sb1) ----------------
__global__ __launch_bounds__(256) void k_se1(
    const float* __restrict__ sums, const float* __restrict__ sw1, const float* __restrict__ sb1,
    float* __restrict__ s1g)
{
  const int sqc = blockIdx.x, b = blockIdx.y, tid = threadIdx.x;   // 8, 32
  __shared__ float mean[1024];
  for (int i = tid; i < 1024; i += 256) mean[i] = sums[b * 1024 + i] * (1.0f / 784.0f);
  __syncthreads();
  const int row = sqc * 32 + (tid >> 3), part = tid & 7;
  const f32x4* wr = (const f32x4*)(sw1 + (size_t)row * 1024 + part * 128);
  const float* mr = mean + part * 128;
  float acc = 0.f;
  #pragma unroll 8
  for (int i = 0; i < 32; i++) {
    f32x4 wv = wr[i];
    acc += wv[0] * mr[i * 4] + wv[1] * mr[i * 4 + 1] + wv[2] * mr[i * 4 + 2] + wv[3] * mr[i * 4 + 3];
  }
  acc += __shfl_xor(acc, 1); acc += __shfl_xor(acc, 2); acc += __shfl_xor(acc, 4);
  if (part == 0) s1g[b * 256 + row] = fmaxf(acc + sb1[row], 0.f);
}

// ---------------- k_se2: s2 = sigmoid(sw2 . s1 + sb2), + scalar tail outputs ----------------
__global__ __launch_bounds__(256) void k_se2(
    const float* __restrict__ s1g, const float* __restrict__ sw2, const float* __restrict__ sb2,
    float* __restrict__ s2, const unsigned* __restrict__ cnts, float* __restrict__ tail)
{
  const int coc = blockIdx.x, b = blockIdx.y, tid = threadIdx.x;   // 4, 32
  if (coc == 0 && b == 0 && tid == 0) {
    float sp = (float)cnts[0] / 1568.0f;
    float sd = (float)cnts[1] / 25088.0f;
    const float c1 = 1048576.0f, c2 = 589824.0f, c3 = 1048576.0f, mf = 200704.0f;
    float dense  = mf + (c1 + c2 + c3) * 784.0f;
    float sparse = mf + c1 * 784.0f * sd + (c2 + c3) * 784.0f * sp;
    tail[0] = sp; tail[1] = sd; tail[2] = sparse / dense; tail[3] = sparse;
  }
  __shared__ float s1s[256];
  s1s[tid] = s1g[b * 256 + tid];
  __syncthreads();
  const int co = coc * 256 + tid;
  const f32x4* wr = (const f32x4*)(sw2 + (size_t)co * 256);
  float acc = sb2[co];
  #pragma unroll 8
  for (int i = 0; i < 64; i++) {
    f32x4 wv = wr[i];
    acc += wv[0] * s1s[i * 4] + wv[1] * s1s[i * 4 + 1] + wv[2] * s1s[i * 4 + 2] + wv[3] * s1s[i * 4 + 3];
  }
  s2[b * 1024 + co] = 1.0f / (1.0f + __expf(-acc));
}

// ---------------- k_scale: h2T *= s2 (in place) ----------------
__global__ __launch_bounds__(256) void k_scale(bf16* __restrict__ h2T, const float* __restrict__ s2)
{
  size_t idx = ((size_t)blockIdx.x * 256 + threadIdx.x) * 8;
  unsigned b = (unsigned)(idx / 802816u);
  unsigned c = (unsigned)(idx & 1023u);
  const float* sp = s2 + b * 1024 + c;
  bf16x8 v = *(const bf16x8*)(h2T + idx);
  #pragma unroll
  for (int e = 0; e < 8; e++) v[e] = (bf16)((float)v[e] * sp[e]);
  *(bf16x8*)(h2T + idx) = v;
}

// ---------------- launch ----------------
extern "C" void kernel_launch(void* const* d_in, const int* in_sizes, int n_in,
                              void* d_out, int out_size, void* d_ws, size_t ws_size,
                              hipStream_t stream)
{
  const float* x   = (const float*)d_in[0];
  const float* wa  = (const float*)d_in[2];
  const float* ga  = (const float*)d_in[3];
  const float* ba  = (const float*)d_in[4];
  const float* ma  = (const float*)d_in[5];
  const float* va  = (const float*)d_in[6];
  const float* wb  = (const float*)d_in[7];
  const float* gb  = (const float*)d_in[8];
  const float* bb  = (const float*)d_in[9];
  const float* mb  = (const float*)d_in[10];
  const float* vb  = (const float*)d_in[11];
  const float* sw1 = (const float*)d_in[12];
  const float* sb1 = (const float*)d_in[13];
  const float* sw2 = (const float*)d_in[14];
  const float* sb2 = (const float*)d_in[15];
  const float* wc  = (const float*)d_in[16];
  const float* gc  = (const float*)d_in[17];
  const float* bc  = (const float*)d_in[18];
  const float* mc  = (const float*)d_in[19];
  const float* vc  = (const float*)d_in[20];
  const float* mkw = (const float*)d_in[21];
  const float* mkb = (const float*)d_in[22];

  char* ws = (char*)d_ws;
  bf16*  xT      = (bf16*)(ws + 0);              // 51,380,224 (reused as h2T)
  bf16*  h1p     = (bf16*)(ws + 51380224);       // 58,982,400
  bf16*  wa_bf   = (bf16*)(ws + 110362624);      // 2,097,152
  bf16*  wc_bf   = (bf16*)(ws + 112459776);      // 2,097,152
  bf16*  wb_bf   = (bf16*)(ws + 114556928);      // 1,179,648
  bf16*  pooledb = (bf16*)(ws + 115736576);      // 3,211,264
  float* mask7   = (float*)(ws + 118947840);     // 8,192
  float* sums    = (float*)(ws + 118956032);     // 131,072
  float* s1g     = (float*)(ws + 119087104);     // 32,768
  float* s2      = (float*)(ws + 119119872);     // 131,072
  float* bn6     = (float*)(ws + 119250944);     // 24,576
  unsigned* cnts = (unsigned*)(ws + 119275520);  // 8

  float* out = (float*)d_out;

  k_init<<<5184, 256, 0, stream>>>(wa, wc, wb, ga, ba, ma, va, gb, bb, mb, vb, gc, bc, mc, vc,
                                   wa_bf, wc_bf, wb_bf, bn6, sums, cnts, h1p);
  k_cast_pool<<<dim3(7, 16, 32), 256, 0, stream>>>(x, xT, pooledb);
  k_mask<<<32, 256, 0, stream>>>(pooledb, mkw, mkb, mask7, cnts);
  k_conv_a<<<1568, 256, 0, stream>>>(wa_bf, xT, h1p, bn6);
  k_conv_b<<<dim3(32, 16, 4), 256, 0, stream>>>(h1p, wb_bf, xT /*h2T*/, sums, bn6);
  k_se1<<<dim3(8, 32), 256, 0, stream>>>(sums, sw1, sb1, s1g);
  k_se2<<<dim3(4, 32), 256, 0, stream>>>(s1g, sw2, sb2, s2, cnts, out + 25690112);
  k_scale<<<12544, 256, 0, stream>>>(xT, s2);
  k_conv_c<<<1568, 256, 0, stream>>>(xT /*h2T*/, wc_bf, out, bn6, x, mask7);
}